// Round 12
// baseline (137.099 us; speedup 1.0000x reference)
//
#include <hip/hip_runtime.h>

// VectorQuantizer R11 (= R6-redux): input (16,64,64,64) f32, codebook (1024,64) f32.
// out = [quantized (16,64,64,64) f32 | indices (16,64,64) as f32].
//
// R6 was the empirical champion (48 us): prep builds CH (split-f16 -2c hi/lo +
// esq-fold chunk) in d_ws; scan = 1024 blocks x 256 thr, wave = K-quarter x
// 64 tokens, A-frags streamed from global CH (L2-resident, no hot-loop
// barriers), 26 MFMA/tile 3-chain split-f16 (sigma ~6e-5), exact value+slot
// top-2, EPS=1e-3 (16 sigma) -> block-cooperative exact fp32 rescan.
// R11 deltas (structure-only):
//  - B staging conflict-free: float4 -> padded s_raw[64][68] -> scalar reads
//    (2-way aliasing = free) -> hi/lo regs. (R6 had 2.1M conflict cycles.)
//  - LDS 41.5 -> ~22 KB, __launch_bounds__(256,4): 4 blocks/CU co-resident.
//  - rescan: x from s_raw, esq from global; epilogue LDS-free direct stores.

typedef _Float16 v8h  __attribute__((ext_vector_type(8)));
typedef float    v16f __attribute__((ext_vector_type(16)));

constexpr int   D         = 64;
constexpr int   K         = 1024;
constexpr int   HW        = 4096;
constexpr int   DHW       = D * HW;
constexpr int   OUT_ELEMS = 16 * DHW;
constexpr float EPS       = 1e-3f;
constexpr int   RAWS      = 68;      // s_raw row stride: 16B-aligned, bank shift 4

// CH: 32 tiles x 9 chunks x 64 lanes x 8 f16 = 288 KB.
// frag f = t*9+kc; CH[f*512 + lane*8 + j]:
//   kc 0-3: hi of -2*C[row = t*32+(lane&31)][k = kc*16+(lane>>5)*8+j]
//   kc 4-7: lo of same
//   kc 8  : lh==0: j0=e_hi, j1=e_lo (pairs with B5 = ones at k=0,1)

__global__ __launch_bounds__(256) void vq_prep(
    const float* __restrict__ cb, _Float16* __restrict__ CH, float* __restrict__ esq)
{
    const int blk = blockIdx.x, tid = threadIdx.x;
    if (blk < 72) {
        const int gid  = blk * 256 + tid;          // [0, 18432)
        const int lane = gid & 63;
        const int fid  = gid >> 6;                 // [0, 288)
        const int t    = fid / 9;
        const int kc   = fid - 9 * t;
        const int l31  = lane & 31;
        const int lh   = lane >> 5;
        const int cw   = t * 32 + l31;
        v8h h;
        if (kc < 8) {
            const int  kk = kc & 3;
            const bool lo = kc >= 4;
            const float* src = cb + cw * D + kk * 16 + lh * 8;
            #pragma unroll
            for (int j = 0; j < 8; ++j) {
                const float v = -2.0f * src[j];
                const _Float16 vh = (_Float16)v;
                h[j] = lo ? (_Float16)(v - (float)vh) : vh;
            }
        } else {
            #pragma unroll
            for (int j = 0; j < 8; ++j) h[j] = (_Float16)0.0f;
            if (lh == 0) {
                const float4* c4 = (const float4*)(cb + cw * D);
                float a0 = 0.f, a1 = 0.f, a2 = 0.f, a3 = 0.f;
                #pragma unroll
                for (int j = 0; j < 16; ++j) {
                    const float4 c = c4[j];
                    a0 = fmaf(c.x, c.x, a0);
                    a1 = fmaf(c.y, c.y, a1);
                    a2 = fmaf(c.z, c.z, a2);
                    a3 = fmaf(c.w, c.w, a3);
                }
                const float e = (a0 + a1) + (a2 + a3);
                const _Float16 ehi = (_Float16)e;
                h[0] = ehi;
                h[1] = (_Float16)(e - (float)ehi);
            }
        }
        *(v8h*)(CH + (size_t)fid * 512 + lane * 8) = h;
    } else {
        const int cw = (blk - 72) * 256 + tid;     // exact f32 e_sq for rescan
        const float4* c4 = (const float4*)(cb + cw * D);
        float a0 = 0.f, a1 = 0.f, a2 = 0.f, a3 = 0.f;
        #pragma unroll
        for (int j = 0; j < 16; ++j) {
            const float4 c = c4[j];
            a0 = fmaf(c.x, c.x, a0);
            a1 = fmaf(c.y, c.y, a1);
            a2 = fmaf(c.z, c.z, a2);
            a3 = fmaf(c.w, c.w, a3);
        }
        esq[cw] = (a0 + a1) + (a2 + a3);
    }
}

__global__ __launch_bounds__(256, 4) void vq_scan(
    const float* __restrict__ input,
    const float* __restrict__ codebook,
    const _Float16* __restrict__ CH,
    const float* __restrict__ esq,
    float* __restrict__ out)
{
    __shared__ float s_raw[64][RAWS];   // 17.4 KB raw x tokens (d-major, padded)
    __shared__ float s_pv[4][64];
    __shared__ float s_p2[4][64];
    __shared__ int   s_pk[4][64];
    __shared__ int   s_idx[64];
    __shared__ int   s_list[64];
    __shared__ int   s_cnt;
    __shared__ float s_xf[64];
    __shared__ float s_redv[4];
    __shared__ int   s_redk[4];

    const int tid  = threadIdx.x;
    const int lane = tid & 63;
    const int q    = __builtin_amdgcn_readfirstlane(tid >> 6);  // K-quarter
    const int lh   = lane >> 5;
    const int tok0 = blockIdx.x * 64;
    const int b    = tok0 >> 12;
    const int hwb  = tok0 & 4095;

    if (tid == 0) s_cnt = 0;

    // ---- B raw staging: coalesced float4 global -> conflict-free LDS ----
    {
        const float* xb = input + (size_t)b * DHW + hwb;
        #pragma unroll
        for (int pass = 0; pass < 4; ++pass) {
            const int d   = pass * 16 + (tid >> 4);
            const int hw4 = (tid & 15) * 4;
            *(float4*)&s_raw[d][hw4] = *(const float4*)(xb + (size_t)d * HW + hw4);
        }
    }
    __syncthreads();

    // ---- B fragments from s_raw: scalar reads (2-way = free), hi/lo regs ----
    v8h bh[2][4], bl[2][4];
    #pragma unroll
    for (int ct = 0; ct < 2; ++ct) {
        const int tok = ct * 32 + (lane & 31);
        #pragma unroll
        for (int kc = 0; kc < 4; ++kc)
            #pragma unroll
            for (int j = 0; j < 8; ++j) {
                const float f = s_raw[kc * 16 + lh * 8 + j][tok];
                const _Float16 fh = (_Float16)f;
                bh[ct][kc][j] = fh;
                bl[ct][kc][j] = (_Float16)(f - (float)fh);
            }
    }

    // B5: ones at k=0,1 (pairs with esq chunk)
    v8h b5 = {};
    if (lh == 0) { b5[0] = (_Float16)1.0f; b5[1] = (_Float16)1.0f; }

    v16f Z = {0,0,0,0,0,0,0,0,0,0,0,0,0,0,0,0};
    const float INF = __builtin_huge_valf();
    float bv0 = INF, b20 = INF, bv1 = INF, b21 = INF;
    int   sl0 = 0, sl1 = 0;

    const v8h* Abase = (const v8h*)CH + lane;

    // ---- hot loop: 8 tiles x 26 MFMA (R6-verified), A streamed from global ----
    #pragma unroll 2
    for (int t = 0; t < 8; ++t) {
        const v8h* Ap = Abase + (size_t)((q * 8 + t) * 9) * 64;
        const v8h ah0 = Ap[0],   ah1 = Ap[64],  ah2 = Ap[128], ah3 = Ap[192];
        const v8h al0 = Ap[256], al1 = Ap[320], al2 = Ap[384], al3 = Ap[448];
        const v8h ae  = Ap[512];

        v16f acc0 = __builtin_amdgcn_mfma_f32_32x32x16_f16(ae, b5, Z, 0, 0, 0);
        v16f acc1 = __builtin_amdgcn_mfma_f32_32x32x16_f16(ae, b5, Z, 0, 0, 0);

        acc0 = __builtin_amdgcn_mfma_f32_32x32x16_f16(ah0, bh[0][0], acc0, 0, 0, 0);
        acc1 = __builtin_amdgcn_mfma_f32_32x32x16_f16(ah0, bh[1][0], acc1, 0, 0, 0);
        acc0 = __builtin_amdgcn_mfma_f32_32x32x16_f16(ah1, bh[0][1], acc0, 0, 0, 0);
        acc1 = __builtin_amdgcn_mfma_f32_32x32x16_f16(ah1, bh[1][1], acc1, 0, 0, 0);
        acc0 = __builtin_amdgcn_mfma_f32_32x32x16_f16(ah2, bh[0][2], acc0, 0, 0, 0);
        acc1 = __builtin_amdgcn_mfma_f32_32x32x16_f16(ah2, bh[1][2], acc1, 0, 0, 0);
        acc0 = __builtin_amdgcn_mfma_f32_32x32x16_f16(ah3, bh[0][3], acc0, 0, 0, 0);
        acc1 = __builtin_amdgcn_mfma_f32_32x32x16_f16(ah3, bh[1][3], acc1, 0, 0, 0);

        acc0 = __builtin_amdgcn_mfma_f32_32x32x16_f16(ah0, bl[0][0], acc0, 0, 0, 0);
        acc1 = __builtin_amdgcn_mfma_f32_32x32x16_f16(ah0, bl[1][0], acc1, 0, 0, 0);
        acc0 = __builtin_amdgcn_mfma_f32_32x32x16_f16(ah1, bl[0][1], acc0, 0, 0, 0);
        acc1 = __builtin_amdgcn_mfma_f32_32x32x16_f16(ah1, bl[1][1], acc1, 0, 0, 0);
        acc0 = __builtin_amdgcn_mfma_f32_32x32x16_f16(ah2, bl[0][2], acc0, 0, 0, 0);
        acc1 = __builtin_amdgcn_mfma_f32_32x32x16_f16(ah2, bl[1][2], acc1, 0, 0, 0);
        acc0 = __builtin_amdgcn_mfma_f32_32x32x16_f16(ah3, bl[0][3], acc0, 0, 0, 0);
        acc1 = __builtin_amdgcn_mfma_f32_32x32x16_f16(ah3, bl[1][3], acc1, 0, 0, 0);

        acc0 = __builtin_amdgcn_mfma_f32_32x32x16_f16(al0, bh[0][0], acc0, 0, 0, 0);
        acc1 = __builtin_amdgcn_mfma_f32_32x32x16_f16(al0, bh[1][0], acc1, 0, 0, 0);
        acc0 = __builtin_amdgcn_mfma_f32_32x32x16_f16(al1, bh[0][1], acc0, 0, 0, 0);
        acc1 = __builtin_amdgcn_mfma_f32_32x32x16_f16(al1, bh[1][1], acc1, 0, 0, 0);
        acc0 = __builtin_amdgcn_mfma_f32_32x32x16_f16(al2, bh[0][2], acc0, 0, 0, 0);
        acc1 = __builtin_amdgcn_mfma_f32_32x32x16_f16(al2, bh[1][2], acc1, 0, 0, 0);
        acc0 = __builtin_amdgcn_mfma_f32_32x32x16_f16(al3, bh[0][3], acc0, 0, 0, 0);
        acc1 = __builtin_amdgcn_mfma_f32_32x32x16_f16(al3, bh[1][3], acc1, 0, 0, 0);

        // exact value+slot top-2 tracking (R6-verified)
        #pragma unroll
        for (int r = 0; r < 16; ++r) {
            const int slot = (t << 4) | r;
            const float s0 = acc0[r];
            b20 = __builtin_amdgcn_fmed3f(s0, bv0, b20);
            if (s0 < bv0) { bv0 = s0; sl0 = slot; }
            const float s1 = acc1[r];
            b21 = __builtin_amdgcn_fmed3f(s1, bv1, b21);
            if (s1 < bv1) { bv1 = s1; sl1 = slot; }
        }
    }

    // ---- cross-half-row merge (lane <-> lane^32), decode cw ----
    #pragma unroll
    for (int ct = 0; ct < 2; ++ct) {
        const float bv = ct ? bv1 : bv0;
        const float b2 = ct ? b21 : b20;
        const int   sl = ct ? sl1 : sl0;
        const float obv = __shfl_xor(bv, 32, 64);
        const float ob2 = __shfl_xor(b2, 32, 64);
        const int   osl = __shfl_xor(sl, 32, 64);
        const bool  oth = obv < bv;            // strict: ties keep own; exact ties flagged
        const float B1  = oth ? obv : bv;
        const float B2  = fminf(fmaxf(bv, obv), fminf(b2, ob2));
        const int   wsl = oth ? osl : sl;
        const int   wlh = oth ? (lh ^ 1) : lh;
        const int   r   = wsl & 15;
        const int   tt  = wsl >> 4;
        const int   cw  = (q * 8 + tt) * 32 + (r & 3) + 8 * (r >> 2) + 4 * wlh;
        if (lane < 32) {
            s_pv[q][ct * 32 + lane] = B1;
            s_p2[q][ct * 32 + lane] = B2;
            s_pk[q][ct * 32 + lane] = cw;
        }
    }
    __syncthreads();

    // ---- merge 4 quarters per token; flag near-ties into list ----
    if (tid < 64) {
        float B1 = INF, B2 = INF; int CW = 0;
        #pragma unroll
        for (int qq = 0; qq < 4; ++qq) {
            const float pv = s_pv[qq][tid];
            const float p2 = s_p2[qq][tid];
            const int   pk = s_pk[qq][tid];
            if (pv < B1) { B2 = fminf(B1, p2); B1 = pv; CW = pk; }
            else         { B2 = fminf(B2, pv); }
        }
        s_idx[tid] = CW;
        if (B2 - B1 < EPS) {
            const int p = atomicAdd(&s_cnt, 1);
            s_list[p] = tid;
        }
    }
    __syncthreads();

    // ---- exact fp32 rescan, block-cooperative (rare: ~1e-4 of tokens) ----
    {
        const int cnt = s_cnt;
        const int rr  = tid >> 2;   // codeword row within 64-chunk
        const int c   = tid & 3;    // d-quarter
        for (int ii = 0; ii < cnt; ++ii) {
            const int tl = s_list[ii];
            if (tid < 64) s_xf[tid] = s_raw[tid][tl];
            __syncthreads();
            const float4* xs4 = (const float4*)&s_xf[c * 16];
            const float4 x0 = xs4[0], x1 = xs4[1], x2 = xs4[2], x3 = xs4[3];
            float bestv = INF; int bestk = K;
            #pragma unroll 4
            for (int i = 0; i < 16; ++i) {
                const int k = i * 64 + rr;                 // ascending per thread
                const float4* c4 = (const float4*)(codebook + (size_t)k * D + c * 16);
                const float4 c0 = c4[0], c1 = c4[1], c2 = c4[2], c3 = c4[3];
                float p0 = 0.f, p1 = 0.f, p2 = 0.f, p3 = 0.f;
                p0 = fmaf(x0.x, c0.x, p0); p0 = fmaf(x0.y, c0.y, p0);
                p0 = fmaf(x0.z, c0.z, p0); p0 = fmaf(x0.w, c0.w, p0);
                p1 = fmaf(x1.x, c1.x, p1); p1 = fmaf(x1.y, c1.y, p1);
                p1 = fmaf(x1.z, c1.z, p1); p1 = fmaf(x1.w, c1.w, p1);
                p2 = fmaf(x2.x, c2.x, p2); p2 = fmaf(x2.y, c2.y, p2);
                p2 = fmaf(x2.z, c2.z, p2); p2 = fmaf(x2.w, c2.w, p2);
                p3 = fmaf(x3.x, c3.x, p3); p3 = fmaf(x3.y, c3.y, p3);
                p3 = fmaf(x3.z, c3.z, p3); p3 = fmaf(x3.w, c3.w, p3);
                float dp = (p0 + p1) + (p2 + p3);
                dp += __shfl_xor(dp, 1, 64);               // sum over d-quarters
                dp += __shfl_xor(dp, 2, 64);
                const float s = fmaf(-2.0f, dp, esq[k]);
                if (s < bestv) { bestv = s; bestk = k; }
            }
            #pragma unroll
            for (int off = 4; off <= 32; off <<= 1) {      // reduce over rows in wave
                const float ov = __shfl_xor(bestv, off, 64);
                const int   ok = __shfl_xor(bestk, off, 64);
                if (ov < bestv || (ov == bestv && ok < bestk)) { bestv = ov; bestk = ok; }
            }
            if (lane == 0) { s_redv[q] = bestv; s_redk[q] = bestk; }
            __syncthreads();
            if (tid == 0) {
                float bb = s_redv[0]; int bk = s_redk[0];
                #pragma unroll
                for (int w = 1; w < 4; ++w) {
                    const float v = s_redv[w]; const int kk = s_redk[w];
                    if (v < bb || (v == bb && kk < bk)) { bb = v; bk = kk; }
                }
                s_idx[tl] = bk;
            }
            __syncthreads();
        }
    }

    // ---- epilogue: per-channel coalesced stores (thread = token x d-quarter) ----
    {
        const int token = tid & 63;
        const int dq    = tid >> 6;                        // 0..3
        const int idx   = s_idx[token];
        const float4* c4 = (const float4*)(codebook + (size_t)idx * D + dq * 16);
        float4 cr[4];
        #pragma unroll
        for (int j = 0; j < 4; ++j) cr[j] = c4[j];
        float* ob = out + (size_t)b * DHW + (size_t)dq * 16 * HW + hwb + token;
        #pragma unroll
        for (int j = 0; j < 4; ++j) {
            ob[(size_t)(4 * j + 0) * HW] = cr[j].x;
            ob[(size_t)(4 * j + 1) * HW] = cr[j].y;
            ob[(size_t)(4 * j + 2) * HW] = cr[j].z;
            ob[(size_t)(4 * j + 3) * HW] = cr[j].w;
        }
        if (tid < 64) out[OUT_ELEMS + tok0 + tid] = (float)s_idx[tid];
    }
}

extern "C" void kernel_launch(void* const* d_in, const int* in_sizes, int n_in,
                              void* d_out, int out_size, void* d_ws, size_t ws_size,
                              hipStream_t stream) {
    const float* input    = (const float*)d_in[0];
    const float* codebook = (const float*)d_in[1];
    float* out            = (float*)d_out;

    _Float16* CH  = (_Float16*)d_ws;                   // 294912 B
    float*    esq = (float*)((char*)d_ws + 294912);    // 4096 B

    vq_prep<<<76, 256, 0, stream>>>(codebook, CH, esq);
    vq_scan<<<1024, 256, 0, stream>>>(input, codebook, CH, esq, out);
}